// Round 2
// baseline (436.013 us; speedup 1.0000x reference)
//
#include <hip/hip_runtime.h>
#include <hip/hip_bf16.h>

// Downsample: ternary-quantized conv3x3 stride2 pad1, NCHW.
// x:(32,384,64,64) f32, w:(384,384,3,3) f32, bias:(384,) f32 -> out:(32,384,32,32) f32
// Implicit GEMM: M=32768 (n,oh,ow), N=384 (o), K=3456 ((kh,kw,c)), bf16 MFMA.
// Round 5: FUSED layout transform -- nhwc_kernel and the xn buffer are GONE.
// conv_gemm stages X directly from NCHW f32: per K-step each thread does
// 8x global_load_dwordx4 (aligned, stride-2 parity extract per kw), f32->bf16
// cvt, 2x ds_write_b128 into the SAME octet-XOR LDS layout the read side
// already uses (read side / W path / epilogue unchanged from the verified
// kernel). Conv zero-padding handled in-register (wave-uniform branches).
// Schedule: 4 phases, 2 barriers per K-step, counted vmcnt (11 / 3+lgkm0),
// never 0 in the main loop. K-order: cc-outer, (kh,kw)-inner so the parity
// over-fetch is L1/L2-absorbed by adjacent kw steps.
// Deterministic: no atomics anywhere.

#define CIN   384
#define HIN   64
#define WIN   64
#define OHW   32
#define KDIM  3456          // 9*384
#define NWELT 1327104       // 384*384*9
#define MDIM  32768         // 32*32*32
#define NT    54            // K-steps of 64 (s = cc*9 + khkw)

using bf16 = __hip_bfloat16;
typedef __attribute__((ext_vector_type(8))) short short8;   // MFMA A/B frag (8 bf16)
typedef __attribute__((ext_vector_type(4))) float floatx4;  // MFMA C/D frag

#define AS1 __attribute__((address_space(1)))
#define AS3 __attribute__((address_space(3)))
#define DMA16(g, l) __builtin_amdgcn_global_load_lds((const AS1 void*)(g), (AS3 void*)(l), 16, 0, 0)

// phase edge: counted vmem wait (+optional lgkm drain) + raw barrier + sched fence.
#define EDGE_V(N) do { \
    asm volatile("s_waitcnt vmcnt(" #N ")" ::: "memory"); \
    __builtin_amdgcn_s_barrier(); \
    __builtin_amdgcn_sched_barrier(0); \
} while (0)
#define EDGE_VL(N) do { \
    asm volatile("s_waitcnt vmcnt(" #N ")" ::: "memory"); \
    asm volatile("s_waitcnt lgkmcnt(0)" ::: "memory"); \
    __builtin_amdgcn_s_barrier(); \
    __builtin_amdgcn_sched_barrier(0); \
} while (0)

// ws layout (floats): [0]=alpha, [1]=thr, [2..64)=62 partials.
// bytes [WQ_OFF, +2654208): Wq bf16 [384][3456] (k=(kh*3+kw)*384+c)
#define NPART  62
#define ZG_F   16
#define WQ_OFF (256 + 100663296)

// ---- Stage 1: fixed-slot partial sums of |w| (no atomics -> deterministic) ----
__global__ void absum_part(const float* __restrict__ w, float* __restrict__ ws) {
    const float4* w4 = (const float4*)w;
    float s = 0.f;
    for (int i = blockIdx.x * 256 + threadIdx.x; i < NWELT / 4; i += NPART * 256) {
        float4 v = w4[i];
        s += fabsf(v.x) + fabsf(v.y) + fabsf(v.z) + fabsf(v.w);
    }
    for (int off = 32; off; off >>= 1) s += __shfl_down(s, off, 64);
    __shared__ float red[4];
    if ((threadIdx.x & 63) == 0) red[threadIdx.x >> 6] = s;
    __syncthreads();
    if (threadIdx.x == 0) ws[2 + blockIdx.x] = red[0] + red[1] + red[2] + red[3];
}

// ---- Stage 2: fixed-order final reduction ----
__global__ void absum_final(float* __restrict__ ws) {
    if (threadIdx.x == 0) {
        float s = 0.f;
        for (int i = 0; i < NPART; ++i) s += ws[2 + i];
        float alpha = s * (1.0f / NWELT);
        ws[0] = alpha;
        ws[1] = 1e-3f * alpha;
        ws[ZG_F + 0] = 0.f; ws[ZG_F + 1] = 0.f;
        ws[ZG_F + 2] = 0.f; ws[ZG_F + 3] = 0.f;
    }
}

// ---- Ternary quantize, output-indexed (coalesced 2B writes; reads L2/L3-hot) ----
__global__ void quant_kernel(const float* __restrict__ w, const float* __restrict__ ws,
                             bf16* __restrict__ wq) {
    int j = blockIdx.x * 256 + threadIdx.x;   // j = o*3456 + (kh*3+kw)*384 + c
    if (j >= NWELT) return;
    float thr = ws[1];
    int o = j / KDIM;
    int rmd = j - o * KDIM;
    int khkw = rmd / 384;
    int c = rmd - khkw * 384;
    float v = w[((o * 384 + c) * 9) + khkw];
    float q = (v > thr) ? 1.f : ((v < -thr) ? -1.f : 0.f);
    wq[j] = __float2bfloat16(q);
}

// ---- GEMM: D[o][m] = sum_k Wq[o][k] * X[m][k]. A=Wq (384 rows), B=X (128 rows). ----
// Halves: A0=o[0,192) A1=o[192,384); B0=m[0,64) B1=m[64,128).
// Wave wv: io=wv&3 (o-pos, x48/half), im=wv>>2 (m-pos, x32/half).
// Phase consumption: P1(A0,B0) P2(A0,B1) P3(A1,B1) P4(A1,B0-from-regs).
// Stage (step s=t+1 during t): P1: X-loads(8, regs) + A0 W-DMA(3);
//                              P3: cvt + 2x ds_write_b128 (X into next buf);
//                              P4: A1 W-DMA(3).
// Per-wave vmem FIFO entering P1 of t: {A1_t(3)}. P1 issues X(8)+A0(3) -> 14.
// P2 edge vmcnt(11)+barrier: A1_t landed (cross-wave). P3: compiler waits own
// X regs; P4 edge vmcnt(3)+lgkmcnt(0)+barrier: A0_{t+1} landed + X published.
// LDS row (64 k-elems, 128B): slot(r,oct)=r*128+(oct^(r&7))*16. W via DMA16
// with pre-swizzled global octet g=(lane&7)^(lane>>3); X via swizzled ds_write.
// X staging threads: co=tid&7 (c-octet), owp=(tid>>3)&15 (ow-pair), ohx=tid>>7
// (wave-uniform). Per c-row i<8: dwordx4 window f32[owp*4..+4) of row
// (cc*64+co*8+i, ih=2*(oh0+ohx)+kh-1). kw=1 -> sel {.x,.z}, ow=owp*2+{0,1};
// kw=2 -> {.y,.w}, ow=owp*2+{0,1}; kw=0 -> {.y,.w}, ow=owp*2+{1,2} (drop
// ow=32 at owp=15; owp=0 writes zeros at ow=0 = iw-pad). ih<0 -> zero rows.
#define BM  128

#define CVT(f) ((short)__builtin_bit_cast(unsigned short, __float2bfloat16(f)))

__device__ __forceinline__ void xput(bf16* lXn, int m, int co, short8 v) {
    *(short8*)((char*)lXn + m * 128 + ((co ^ (m & 7)) << 4)) = v;
}

__global__ __launch_bounds__(512, 2) void conv_gemm(const float* __restrict__ x,
                                                    const bf16* __restrict__ wq,
                                                    const float* __restrict__ ws,
                                                    const float* __restrict__ bias,
                                                    float* __restrict__ out) {
    __shared__ __align__(16) bf16 lW[2][384 * 64];   // 96 KiB
    __shared__ __align__(16) bf16 lX[2][128 * 64];   // 32 KiB
    const int m_base = blockIdx.x * BM;              // 256 blocks
    const int tid = threadIdx.x;
    const int lane = tid & 63;
    const int wv = tid >> 6;          // 0..7
    const int io = wv & 3;            // o wave-position (x48 per half)
    const int im = wv >> 2;           // m wave-position (x32 per half)
    const int g = (lane & 7) ^ (lane >> 3);          // pre-swizzled global octet

    const int n = m_base >> 10;                      // single n per block
    const int oh0 = (m_base >> 5) & 31;              // 4 oh rows per block

    // ---- W staging descriptors (unchanged, verified) ----
    const bf16* pw[2][3];
    int wLoff[2][3];
    #pragma unroll
    for (int h = 0; h < 2; ++h)
        #pragma unroll
        for (int j = 0; j < 3; ++j) {
            int rr = h * 192 + wv * 24 + j * 8;
            pw[h][j] = wq + (size_t)(rr + (lane >> 3)) * KDIM + g * 8;
            wLoff[h][j] = rr * 64;
        }

    // ---- X staging descriptors ----
    const int co  = tid & 7;
    const int owp = (tid >> 3) & 15;
    const int ohx = tid >> 7;                        // wave-uniform (= wv>>1)
    const int ohb = 2 * (oh0 + ohx) - 1;             // ih = ohb + kh
    const float* xrow0 = x + ((size_t)(n * CIN + co * 8) * HIN) * WIN + owp * 4;
    // full row addr for step: xrow0 + (cc*64 rows)*4096 + ih*64 ; +i*4096 per c

    // ---- ds_read offsets (element units; unchanged, verified) ----
    const int l15 = lane & 15, quad = lane >> 4, l7 = lane & 7;
    const int octA = (quad ^ l7) * 8;         // ks=0 slot
    const int octB = ((4 + quad) ^ l7) * 8;   // ks=1 slot
    int aoff[2][3], boff[2][2];
    #pragma unroll
    for (int h = 0; h < 2; ++h)
        #pragma unroll
        for (int fo = 0; fo < 3; ++fo)
            aoff[h][fo] = (h * 192 + io * 48 + fo * 16 + l15) * 64;
    #pragma unroll
    for (int h = 0; h < 2; ++h)
        #pragma unroll
        for (int fm = 0; fm < 2; ++fm)
            boff[h][fm] = (h * 64 + im * 32 + fm * 16 + l15) * 64;

    floatx4 acc[6][4];
    #pragma unroll
    for (int i = 0; i < 6; ++i)
        #pragma unroll
        for (int j = 0; j < 4; ++j)
            acc[i][j] = (floatx4){0.f, 0.f, 0.f, 0.f};

    short8 zv;
    #pragma unroll
    for (int i = 0; i < 8; ++i) zv[i] = 0;

    // ================= prologue: stage step 0 (cc=0,kh=0,kw=0) into buf 0 =========
    {
        float4 xr[8];
        const int ihv = ohb;          // kh=0
        if (ihv >= 0) {
            const float* xb = xrow0 + (size_t)ihv * WIN;
            #pragma unroll
            for (int i = 0; i < 8; ++i) xr[i] = *(const float4*)(xb + i * 4096);
        } else {
            #pragma unroll
            for (int i = 0; i < 8; ++i) xr[i] = make_float4(0.f, 0.f, 0.f, 0.f);
        }
        #pragma unroll
        for (int j = 0; j < 3; ++j) DMA16(pw[0][j], &lW[0][wLoff[0][j]]);     // A0_0
        #pragma unroll
        for (int j = 0; j < 3; ++j) DMA16(pw[1][j], &lW[0][wLoff[1][j]]);     // A1_0
        // cvt + store (kw=0 path): sel {.y,.w} -> ow = owp*2 + {1,2}
        short8 v0, v1;
        if (ihv >= 0) {
            #pragma unroll
            for (int i = 0; i < 8; ++i) { v0[i] = CVT(xr[i].y); v1[i] = CVT(xr[i].w); }
        } else { v0 = zv; v1 = zv; }
        xput(lX[0], ohx * 32 + owp * 2 + 1, co, v0);
        if (owp < 15) xput(lX[0], ohx * 32 + owp * 2 + 2, co, v1);
        if (owp == 0) xput(lX[0], ohx * 32, co, zv);
        asm volatile("s_waitcnt lgkmcnt(0)" ::: "memory");
        asm volatile("s_waitcnt vmcnt(3)" ::: "memory");    // A0_0 landed; A1_0 flying
        __builtin_amdgcn_s_barrier();
        __builtin_amdgcn_sched_barrier(0);
    }

    short8 af[2][3], bfl[2][2], bfh[2][2];

    for (int t = 0; t < NT - 1; ++t) {
        bf16* lWc = lW[t & 1];
        bf16* lXc = lX[t & 1];
        bf16* lWn = lW[(t & 1) ^ 1];
        bf16* lXn = lX[(t & 1) ^ 1];
        // next-step scalars (s = t+1); order: cc outer, khkw inner
        const int s = t + 1;
        const int cc_s = s / 9;
        const int khkw_s = s - cc_s * 9;
        const int kh_s = khkw_s / 3;
        const int kw_s = khkw_s - kh_s * 3;
        const int koff = khkw_s * 384 + cc_s * 64;   // W k-offset (elements)
        const int ihv = ohb + kh_s;

        // ---- P1: ds_read af(A0)+bfl(B0); issue X-loads(s); W A0(s); MFMA q00 ----
        #pragma unroll
        for (int fo = 0; fo < 3; ++fo) {
            af[0][fo] = *(const short8*)(lWc + aoff[0][fo] + octA);
            af[1][fo] = *(const short8*)(lWc + aoff[0][fo] + octB);
        }
        #pragma unroll
        for (int fm = 0; fm < 2; ++fm) {
            bfl[0][fm] = *(const short8*)(lXc + boff[0][fm] + octA);
            bfl[1][fm] = *(const short8*)(lXc + boff[0][fm] + octB);
        }
        float4 xr[8];
        if (ihv >= 0) {
            const float* xb = xrow0 + ((size_t)cc_s * 64 * HIN + ihv) * WIN;
            #pragma unroll
            for (int i = 0; i < 8; ++i) xr[i] = *(const float4*)(xb + i * 4096);
        } else {
            #pragma unroll
            for (int i = 0; i < 8; ++i) xr[i] = make_float4(0.f, 0.f, 0.f, 0.f);
        }
        #pragma unroll
        for (int j = 0; j < 3; ++j) DMA16(pw[0][j] + koff, lWn + wLoff[0][j]);
        __builtin_amdgcn_s_setprio(1);
        #pragma unroll
        for (int ks = 0; ks < 2; ++ks)
            #pragma unroll
            for (int fo = 0; fo < 3; ++fo)
                #pragma unroll
                for (int fm = 0; fm < 2; ++fm)
                    acc[fo][fm] = __builtin_amdgcn_mfma_f32_16x16x32_bf16(
                        af[ks][fo], bfl[ks][fm], acc[fo][fm], 0, 0, 0);
        __builtin_amdgcn_s_setprio(0);

        // ---- P2: ds_read bfh(B1); EDGE vmcnt(11) -> A1_t landed; MFMA q01 ----
        #pragma unroll
        for (int fm = 0; fm < 2; ++fm) {
            bfh[0][fm] = *(const short8*)(lXc + boff[1][fm] + octA);
            bfh[1][fm] = *(const short8*)(lXc + boff[1][fm] + octB);
        }
        EDGE_V(11);
        __builtin_amdgcn_s_setprio(1);
        #pragma unroll
        for (int ks = 0; ks < 2; ++ks)
            #pragma unroll
            for (int fo = 0; fo < 3; ++fo)
                #pragma unroll
                for (int fm = 0; fm < 2; ++fm)
                    acc[fo][2 + fm] = __builtin_amdgcn_mfma_f32_16x16x32_bf16(
                        af[ks][fo], bfh[ks][fm], acc[fo][2 + fm], 0, 0, 0);
        __builtin_amdgcn_s_setprio(0);

        // ---- P3: ds_read af(A1); MFMA q11; then cvt+publish X(s) into next buf ----
        #pragma unroll
        for (int fo = 0; fo < 3; ++fo) {
            af[0][fo] = *(const short8*)(lWc + aoff[1][fo] + octA);
            af[1][fo] = *(const short8*)(lWc + aoff[1][fo] + octB);
        }
        __builtin_amdgcn_s_setprio(1);
        #pragma unroll
        for (int ks = 0; ks < 2; ++ks)
            #pragma unroll
            for (int fo = 0; fo < 3; ++fo)
                #pragma unroll
                for (int fm = 0; fm < 2; ++fm)
                    acc[3 + fo][2 + fm] = __builtin_amdgcn_mfma_f32_16x16x32_bf16(
                        af[ks][fo], bfh[ks][fm], acc[3 + fo][2 + fm], 0, 0, 0);
        __builtin_amdgcn_s_setprio(0);
        {
            short8 v0, v1;
            if (ihv >= 0) {
                if (kw_s == 1) {
                    #pragma unroll
                    for (int i = 0; i < 8; ++i) { v0[i] = CVT(xr[i].x); v1[i] = CVT(xr[i].z); }
                } else {
                    #pragma unroll
                    for (int i = 0; i < 8; ++i) { v0[i] = CVT(xr[i].y); v1[i] = CVT(xr[i].w); }
                }
            } else { v0 = zv; v1 = zv; }
            if (kw_s == 0) {
                xput(lXn, ohx * 32 + owp * 2 + 1, co, v0);
                if (owp < 15) xput(lXn, ohx * 32 + owp * 2 + 2, co, v1);
                if (owp == 0) xput(lXn, ohx * 32, co, zv);
            } else {
                xput(lXn, ohx * 32 + owp * 2, co, v0);
                xput(lXn, ohx * 32 + owp * 2 + 1, co, v1);
            }
        }

        // ---- P4: W A1(s); EDGE vmcnt(3)+lgkm0 -> A0_{t+1} + X published; MFMA q10 ----
        #pragma unroll
        for (int j = 0; j < 3; ++j) DMA16(pw[1][j] + koff, lWn + wLoff[1][j]);
        EDGE_VL(3);
        __builtin_amdgcn_s_setprio(1);
        #pragma unroll
        for (int ks = 0; ks < 2; ++ks)
            #pragma unroll
            for (int fo = 0; fo < 3; ++fo)
                #pragma unroll
                for (int fm = 0; fm < 2; ++fm)
                    acc[3 + fo][fm] = __builtin_amdgcn_mfma_f32_16x16x32_bf16(
                        af[ks][fo], bfl[ks][fm], acc[3 + fo][fm], 0, 0, 0);
        __builtin_amdgcn_s_setprio(0);
    }

    // ---- peeled tail tile (t = 53, buf 1): no staging, tight waits ----
    {
        bf16* lWc = lW[1];
        bf16* lXc = lX[1];
        // P1
        #pragma unroll
        for (int fo = 0; fo < 3; ++fo) {
            af[0][fo] = *(const short8*)(lWc + aoff[0][fo] + octA);
            af[1][fo] = *(const short8*)(lWc + aoff[0][fo] + octB);
        }
        #pragma unroll
        for (int fm = 0; fm < 2; ++fm) {
            bfl[0][fm] = *(const short8*)(lXc + boff[0][fm] + octA);
            bfl[1][fm] = *(const short8*)(lXc + boff[0][fm] + octB);
        }
        __builtin_amdgcn_s_setprio(1);
        #pragma unroll
        for (int ks = 0; ks < 2; ++ks)
            #pragma unroll
            for (int fo = 0; fo < 3; ++fo)
                #pragma unroll
                for (int fm = 0; fm < 2; ++fm)
                    acc[fo][fm] = __builtin_amdgcn_mfma_f32_16x16x32_bf16(
                        af[ks][fo], bfl[ks][fm], acc[fo][fm], 0, 0, 0);
        __builtin_amdgcn_s_setprio(0);
        // P2: A1_53 still in flight -> drain + barrier
        #pragma unroll
        for (int fm = 0; fm < 2; ++fm) {
            bfh[0][fm] = *(const short8*)(lXc + boff[1][fm] + octA);
            bfh[1][fm] = *(const short8*)(lXc + boff[1][fm] + octB);
        }
        EDGE_V(0);
        __builtin_amdgcn_s_setprio(1);
        #pragma unroll
        for (int ks = 0; ks < 2; ++ks)
            #pragma unroll
            for (int fo = 0; fo < 3; ++fo)
                #pragma unroll
                for (int fm = 0; fm < 2; ++fm)
                    acc[fo][2 + fm] = __builtin_amdgcn_mfma_f32_16x16x32_bf16(
                        af[ks][fo], bfh[ks][fm], acc[fo][2 + fm], 0, 0, 0);
        __builtin_amdgcn_s_setprio(0);
        // P3
        #pragma unroll
        for (int fo = 0; fo < 3; ++fo) {
            af[0][fo] = *(const short8*)(lWc + aoff[1][fo] + octA);
            af[1][fo] = *(const short8*)(lWc + aoff[1][fo] + octB);
        }
        __builtin_amdgcn_s_setprio(1);
        #pragma unroll
        for (int ks = 0; ks < 2; ++ks)
            #pragma unroll
            for (int fo = 0; fo < 3; ++fo)
                #pragma unroll
                for (int fm = 0; fm < 2; ++fm)
                    acc[3 + fo][2 + fm] = __builtin_amdgcn_mfma_f32_16x16x32_bf16(
                        af[ks][fo], bfh[ks][fm], acc[3 + fo][2 + fm], 0, 0, 0);
        __builtin_amdgcn_s_setprio(0);
        // P4
        __builtin_amdgcn_s_setprio(1);
        #pragma unroll
        for (int ks = 0; ks < 2; ++ks)
            #pragma unroll
            for (int fo = 0; fo < 3; ++fo)
                #pragma unroll
                for (int fm = 0; fm < 2; ++fm)
                    acc[3 + fo][fm] = __builtin_amdgcn_mfma_f32_16x16x32_bf16(
                        af[ks][fo], bfl[ks][fm], acc[3 + fo][fm], 0, 0, 0);
        __builtin_amdgcn_s_setprio(0);
    }

    // ---- epilogue: D row = o (quad*4+reg), col = m (lane&15) -> coalesced along ow ----
    float alpha = ws[0];
    #pragma unroll
    for (int i = 0; i < 6; ++i) {
        int o0 = (i / 3) * 192 + io * 48 + (i % 3) * 16 + quad * 4;
        #pragma unroll
        for (int j = 0; j < 4; ++j) {
            int m = m_base + (j >> 1) * 64 + im * 32 + (j & 1) * 16 + l15;
            int nn = m >> 10, ohh = (m >> 5) & 31, oww = m & 31;
            #pragma unroll
            for (int r = 0; r < 4; ++r) {
                int o = o0 + r;
                out[((nn * 384 + o) * OHW + ohh) * OHW + oww] = alpha * acc[i][j][r] + bias[o];
            }
        }
    }
}

extern "C" void kernel_launch(void* const* d_in, const int* in_sizes, int n_in,
                              void* d_out, int out_size, void* d_ws, size_t ws_size,
                              hipStream_t stream) {
    (void)in_sizes; (void)n_in; (void)out_size; (void)ws_size;
    const float* x    = (const float*)d_in[0];
    const float* w    = (const float*)d_in[1];
    const float* bias = (const float*)d_in[2];
    float* out = (float*)d_out;
    float* wsf = (float*)d_ws;
    bf16* wq = (bf16*)((char*)d_ws + WQ_OFF);

    absum_part<<<NPART, 256, 0, stream>>>(w, wsf);
    absum_final<<<1, 64, 0, stream>>>(wsf);
    quant_kernel<<<(NWELT + 255) / 256, 256, 0, stream>>>(w, wsf, wq);
    conv_gemm<<<dim3(MDIM / BM, 1), 512, 0, stream>>>(x, wq, wsf, bias, out);
}